// Round 2
// baseline (320.441 us; speedup 1.0000x reference)
//
#include <hip/hip_runtime.h>

static constexpr int   kB       = 32;
static constexpr int   kN       = 1024;
static constexpr int   kM       = 1024;
static constexpr float kEps     = 0.1f;
static constexpr float kInvEps  = 10.0f;
static constexpr float kThresh  = 0.05f;
static constexpr int   kMaxIter = 50;
static constexpr float kLogMu   = -6.9314616f;   // log(1/1024 + 1e-8)

__device__ float g_u[kB * kN];
__device__ float g_v[kB * kM];
__device__ float g_part[1024];
__device__ int   g_done_iter;

// ---------------------------------------------------------------- init ----
__global__ __launch_bounds__(256)
void init_kernel()
{
    const int gid = blockIdx.x * 256 + threadIdx.x;   // 16384 threads
    float4* U = (float4*)g_u;                          // 8192 float4
    float4* V = (float4*)g_v;                          // 8192 float4
    const float4 z = make_float4(0.f, 0.f, 0.f, 0.f);
    if (gid < 8192) U[gid] = z;
    else            V[gid - 8192] = z;
    if (gid == 0) g_done_iter = kMaxIter;
}

// ----------------------------------------------------------------- row ----
// u_i = eps*(log_mu - log(sum_j exp((v_j - C_ij)/eps)))   (u cancels)
// grid 1024 blocks x 256 thr; block handles 32 rows (wave: 8 rows)
__global__ __launch_bounds__(256)
void row_kernel(const float* __restrict__ C, int it)
{
    if (it > g_done_iter) return;
    const int blk  = blockIdx.x;
    const int tid  = threadIdx.x;
    const int wv   = tid >> 6;
    const int lane = tid & 63;
    const int b    = blk >> 5;                 // 32 row-blocks per batch
    __shared__ float s_w[4];

    const float4* Vb = (const float4*)(g_v + b * kM);
    const float4 v0 = Vb[lane], v1 = Vb[64 + lane],
                 v2 = Vb[128 + lane], v3 = Vb[192 + lane];

    float werr = 0.f;
    const int row0 = blk * 32 + wv * 8;
    for (int r = 0; r < 8; ++r) {
        const int row = row0 + r;
        const float4* Crow = (const float4*)(C + (size_t)row * kM);
        const float4 c0 = Crow[lane], c1 = Crow[64 + lane],
                     c2 = Crow[128 + lane], c3 = Crow[192 + lane];
        float s = __expf((v0.x - c0.x) * kInvEps) + __expf((v0.y - c0.y) * kInvEps)
                + __expf((v0.z - c0.z) * kInvEps) + __expf((v0.w - c0.w) * kInvEps)
                + __expf((v1.x - c1.x) * kInvEps) + __expf((v1.y - c1.y) * kInvEps)
                + __expf((v1.z - c1.z) * kInvEps) + __expf((v1.w - c1.w) * kInvEps)
                + __expf((v2.x - c2.x) * kInvEps) + __expf((v2.y - c2.y) * kInvEps)
                + __expf((v2.z - c2.z) * kInvEps) + __expf((v2.w - c2.w) * kInvEps)
                + __expf((v3.x - c3.x) * kInvEps) + __expf((v3.y - c3.y) * kInvEps)
                + __expf((v3.z - c3.z) * kInvEps) + __expf((v3.w - c3.w) * kInvEps);
        #pragma unroll
        for (int off = 32; off >= 1; off >>= 1)
            s += __shfl_xor(s, off, 64);
        if (lane == 0) {
            const float unew = kEps * (kLogMu - __logf(s));
            const float uold = g_u[row];
            g_u[row] = unew;
            werr += fabsf(unew - uold);
        }
    }
    if (lane == 0) s_w[wv] = werr;
    __syncthreads();
    if (tid == 0) g_part[blk] = s_w[0] + s_w[1] + s_w[2] + s_w[3];
}

// ----------------------------------------------------------------- col ----
// v_j = eps*(log_nu - log(sum_i exp((u_i - C_ij)/eps)))
// grid 1025 blocks; blk<1024: b=blk>>5, 32-col tile jt=blk&31.
// thread: jj4=tid&7 (4 cols via float4), chunk=tid>>3 (32 rows).
// blk==1024: err reduction + freeze decision.
__global__ __launch_bounds__(256)
void col_kernel(const float* __restrict__ C, int it)
{
    if (it > g_done_iter) return;
    const int blk = blockIdx.x;
    const int tid = threadIdx.x;

    if (blk == 1024) {                        // err reduce (g_part from row)
        __shared__ float s_m[256];
        float e = g_part[tid] + g_part[tid + 256] +
                  g_part[tid + 512] + g_part[tid + 768];
        s_m[tid] = e;
        __syncthreads();
        for (int off = 128; off >= 1; off >>= 1) {
            if (tid < off) s_m[tid] += s_m[tid + off];
            __syncthreads();
        }
        if (tid == 0 && s_m[0] * (1.0f / 32768.0f) < kThresh)
            g_done_iter = it;
        return;
    }

    const int b  = blk >> 5;
    const int jt = blk & 31;
    __shared__ float s_u[32 * 33];            // padded: chunk*33 + i
    __shared__ float s_s[256 * 4];
    for (int t = tid; t < kN; t += 256)
        s_u[(t >> 5) * 33 + (t & 31)] = g_u[b * kN + t];
    __syncthreads();

    const int jj4   = tid & 7;
    const int chunk = tid >> 3;
    const float* up = s_u + chunk * 33;
    const float4* Cq = (const float4*)(C + ((size_t)b * kN + chunk * 32) * kM
                                         + jt * 32 + jj4 * 4);
    float4 s = make_float4(0.f, 0.f, 0.f, 0.f);
    #pragma unroll 8
    for (int i = 0; i < 32; ++i) {
        const float4 cv = Cq[(size_t)i * (kM / 4)];
        const float  ui = up[i];
        s.x += __expf((ui - cv.x) * kInvEps);
        s.y += __expf((ui - cv.y) * kInvEps);
        s.z += __expf((ui - cv.z) * kInvEps);
        s.w += __expf((ui - cv.w) * kInvEps);
    }
    ((float4*)s_s)[tid] = s;                  // s_s[chunk*32 + jj4*4 + k]
    __syncthreads();
    if (tid < 32) {
        float S = 0.f;
        #pragma unroll
        for (int c = 0; c < 32; ++c) S += s_s[c * 32 + tid];
        g_v[b * kM + jt * 32 + tid] = kEps * (kLogMu - __logf(S));
    }
}

// --------------------------------------------------------------- final ----
// pi = exp((u_i + v_j - C_ij)/eps); copy cost; per-block reduced partials.
__global__ __launch_bounds__(256)
void final_kernel(const float* __restrict__ C, float* __restrict__ out)
{
    const int blk = blockIdx.x;               // 1024, 32 rows each
    const int tid = threadIdx.x;
    const int b   = blk >> 5;
    __shared__ float s_w[4];

    float* outPi   = out + kB;
    float* outCost = out + kB + (size_t)kB * kN * kM;

    const float4 vv = ((const float4*)(g_v + b * kM))[tid];
    float acc = 0.f;
    const int row0 = blk * 32;
    for (int r = 0; r < 32; ++r) {
        const int row = row0 + r;
        const float u = g_u[row];
        const float4 cv = ((const float4*)(C + (size_t)row * kM))[tid];
        float4 p;
        p.x = __expf((u + vv.x - cv.x) * kInvEps);
        p.y = __expf((u + vv.y - cv.y) * kInvEps);
        p.z = __expf((u + vv.z - cv.z) * kInvEps);
        p.w = __expf((u + vv.w - cv.w) * kInvEps);
        ((float4*)outPi)[(size_t)row * 256 + tid]   = p;
        ((float4*)outCost)[(size_t)row * 256 + tid] = cv;
        acc += p.x * cv.x + p.y * cv.y + p.z * cv.z + p.w * cv.w;
    }
    #pragma unroll
    for (int off = 32; off >= 1; off >>= 1)
        acc += __shfl_xor(acc, off, 64);
    if ((tid & 63) == 0) s_w[tid >> 6] = acc;
    __syncthreads();
    if (tid == 0) g_part[blk] = s_w[0] + s_w[1] + s_w[2] + s_w[3];
}

// -------------------------------------------------------------- reduce ----
__global__ __launch_bounds__(64)
void reduce_kernel(float* __restrict__ out)
{
    const int t = threadIdx.x;
    if (t < kB) {
        float s = 0.f;
        #pragma unroll
        for (int i = 0; i < 32; ++i) s += g_part[t * 32 + i];
        out[t] = s;
    }
}

// -------------------------------------------------------------- launch ----
extern "C" void kernel_launch(void* const* d_in, const int* in_sizes, int n_in,
                              void* d_out, int out_size, void* d_ws, size_t ws_size,
                              hipStream_t stream)
{
    (void)in_sizes; (void)n_in; (void)d_ws; (void)ws_size; (void)out_size;
    const float* C = (const float*)d_in[0];
    float* out = (float*)d_out;

    init_kernel<<<64, 256, 0, stream>>>();
    for (int it = 0; it < kMaxIter; ++it) {
        row_kernel<<<1024, 256, 0, stream>>>(C, it);
        col_kernel<<<1025, 256, 0, stream>>>(C, it);
    }
    final_kernel<<<1024, 256, 0, stream>>>(C, out);
    reduce_kernel<<<1, 64, 0, stream>>>(out);
}